// Round 15
// baseline (182.903 us; speedup 1.0000x reference)
//
#include <hip/hip_runtime.h>

#define N_NODES 50000
#define N_EDGES 800000
#define N_FEAT 128
#define N_HID 128
#define N_CLS 40
#define BN_EPS 1e-5f

#define CSR_STRIDE 64   // padded CSR row stride; max degree ~40 (Poisson 16)
#define NXCD 8
#define P_NODES 6250    // nodes per XCD partition (50000/8)
#define CSR_B 2048      // CSR-build blocks: 256 per partition (2x r10 in-flight atomics)
#define CSR_BO 256      // blocks per partition
#define WPACK_B 84
#define XPACK_B 3125
#define G2_SUB 51       // gather2 nodes per block

typedef short bf16x8 __attribute__((ext_vector_type(8)));
typedef float f32x4 __attribute__((ext_vector_type(4)));

// RNE float->bf16 helpers
__device__ __forceinline__ unsigned bfpack(float a, float b) {
    unsigned ua = __float_as_uint(a), ub = __float_as_uint(b);
    ua = (ua + 0x7FFFu + ((ua >> 16) & 1u)) >> 16;
    ub = (ub + 0x7FFFu + ((ub >> 16) & 1u)) >> 16;
    return ua | (ub << 16);
}
__device__ __forceinline__ unsigned short bfr1(float a) {
    unsigned u = __float_as_uint(a);
    u = (u + 0x7FFFu + ((u >> 16) & 1u)) >> 16;
    return (unsigned short)u;
}
__device__ __forceinline__ float bflo(unsigned u) { return __uint_as_float(u << 16); }
__device__ __forceinline__ float bfhi(unsigned u) { return __uint_as_float(u & 0xFFFF0000u); }

// ---------------------------------------------------------------------------
// Fused CSR-build + prep, XCD-partitioned. This round's probe: 2048 CSR
// blocks (256/partition) x 4 edges/thread — doubles in-flight atomics per
// partition vs r10-r14 (which pinned at 44-46 us across 6 designs).
// Discriminates latency-hiding-limited vs L2-atomic-service-limited.
// ---------------------------------------------------------------------------
__global__ __launch_bounds__(256) void degprep_kernel(
    const int* __restrict__ src, const int* __restrict__ dst,
    int* __restrict__ deg_i, unsigned short* __restrict__ csr_pad,
    const float* __restrict__ W1l, const float* __restrict__ W1r,
    const float* __restrict__ W2l, const float* __restrict__ W2r,
    const float* __restrict__ x, unsigned* __restrict__ WfA,
    unsigned* __restrict__ WfB, unsigned* __restrict__ x_bf16) {
    int b = blockIdx.x;
    int t = threadIdx.x;
    if (b < CSR_B) {
        const int p = b & (NXCD - 1);
        const int bo = b >> 3;
        const int plo = p * P_NODES;
        const int phi = plo + P_NODES;
        const int4* dst4 = (const int4*)dst;
        const int4* src4 = (const int4*)src;
        // chunks of 1024 edges (256 thr x 4 edges); 782 chunks, ~3/block
        for (int c = bo; c * 1024 < N_EDGES; c += CSR_BO) {
            int e = c * 1024 + t * 4;
            if (e < N_EDGES) {
                int i4 = e >> 2;
                int4 d4 = dst4[i4];
                bool k0 = (d4.x >= plo) && (d4.x < phi);
                bool k1 = (d4.y >= plo) && (d4.y < phi);
                bool k2 = (d4.z >= plo) && (d4.z < phi);
                bool k3 = (d4.w >= plo) && (d4.w < phi);
                if (k0 | k1 | k2 | k3) {
                    int4 s4 = src4[i4];
                    if (k0) { int r = atomicAdd(&deg_i[d4.x], 1);
                        if (r < CSR_STRIDE) csr_pad[d4.x * CSR_STRIDE + r] = (unsigned short)s4.x; }
                    if (k1) { int r = atomicAdd(&deg_i[d4.y], 1);
                        if (r < CSR_STRIDE) csr_pad[d4.y * CSR_STRIDE + r] = (unsigned short)s4.y; }
                    if (k2) { int r = atomicAdd(&deg_i[d4.z], 1);
                        if (r < CSR_STRIDE) csr_pad[d4.z * CSR_STRIDE + r] = (unsigned short)s4.z; }
                    if (k3) { int r = atomicAdd(&deg_i[d4.w], 1);
                        if (r < CSR_STRIDE) csr_pad[d4.w * CSR_STRIDE + r] = (unsigned short)s4.w; }
                }
            }
        }
        return;
    }
    int i = (b - CSR_B) * 256 + t;
    if (b < CSR_B + WPACK_B) {
        if (i < 16384) {
            int f = i >> 8, r = i & 255;
            int lane = r >> 2, u = r & 3;
            int phase = f >> 5, kc = (f >> 3) & 3, nt = f & 7;
            int k0 = phase * 128 + kc * 32 + (lane >> 4) * 8 + u * 2;
            int n = nt * 16 + (lane & 15);
            float w0, w1;
            if (k0 < 128) {
                w0 = W1l[n * 128 + k0];
                w1 = W1l[n * 128 + k0 + 1];
            } else {
                w0 = W1r[n * 128 + k0 - 128];
                w1 = W1r[n * 128 + k0 - 127];
            }
            WfA[i] = bfpack(w0, w1);
        } else if (i < 21504) {
            int j = i - 16384;
            int f = j >> 8, r = j & 255;
            int lane = r >> 2, u = r & 3;
            int kc = f / 5, nt = f % 5;
            int k0 = kc * 32 + (lane >> 4) * 8 + u * 2;
            int n = nt * 16 + (lane & 15);
            float w0, w1;
            if (n < 40) {
                w0 = W2l[n * 128 + k0];
                w1 = W2l[n * 128 + k0 + 1];
            } else {
                w0 = W2r[(n - 40) * 128 + k0];
                w1 = W2r[(n - 40) * 128 + k0 + 1];
            }
            WfB[j] = bfpack(w0, w1);
        }
    } else {
        int j = (b - CSR_B - WPACK_B) * 256 + t;
        if (j < 800000) {
            const float4* xf = (const float4*)x;
            float4 a = xf[(size_t)j * 2];
            float4 bq = xf[(size_t)j * 2 + 1];
            uint4 o;
            o.x = bfpack(a.x, a.y);
            o.y = bfpack(a.z, a.w);
            o.z = bfpack(bq.x, bq.y);
            o.w = bfpack(bq.z, bq.w);
            ((uint4*)x_bf16)[j] = o;
        }
    }
}

// ---------------------------------------------------------------------------
// Fused GATHER1 + GEMM1 + GEMM2 at 16-ROW TILES (3125 blocks) + LDS-staged
// CSR (r14 version, unchanged).
// ---------------------------------------------------------------------------
__global__ __launch_bounds__(256) void gg_kernel(
    const unsigned short* __restrict__ csr_pad, const int* __restrict__ deg_i,
    const unsigned* __restrict__ x_bf16,
    const unsigned* __restrict__ WfA, const unsigned* __restrict__ WfB,
    const float* __restrict__ b1,
    const float* __restrict__ gamma, const float* __restrict__ beta,
    const float* __restrict__ rmean, const float* __restrict__ rvar,
    unsigned short* __restrict__ z2s, float* __restrict__ p2) {
    __shared__ unsigned Asu0[16 * 68];  // gather result, then h (bf16)
    __shared__ unsigned Asu1[16 * 68];  // x tile (bf16)
    __shared__ __align__(16) unsigned short Cs[16 * 64];  // staged CSR rows
    const int t = threadIdx.x;
    const int wid = __builtin_amdgcn_readfirstlane(t >> 6);
    const int lane = t & 63;
    const int li = lane & 15;
    const int quad = lane >> 4;
    const int sg = t >> 4;   // node within tile / stage row
    const int gl = t & 15;   // feature segment
    const int tb = blockIdx.x * 16;   // 3125*16 = 50000, all rows valid
    const uint4* xb4 = (const uint4*)x_bf16;

    // issue x-tile stage load early; latency hides under the gather
    uint4 xs = xb4[(size_t)(tb + sg) * 16 + gl];
    // stage the block's 16 CSR rows: 1024 ushorts = 256 uint2, coalesced
    ((uint2*)Cs)[t] = ((const uint2*)(csr_pad + (size_t)tb * 64))[t];
    __syncthreads();  // Cs visible

    // ---- gather: subgroup sg owns node tb+sg (ILP-8, identical order) ----
    int gid = tb + sg;
    int n = min(deg_i[gid], CSR_STRIDE);
    const unsigned short* cr = Cs + sg * 64;
    float acc[8];
#pragma unroll
    for (int j = 0; j < 8; ++j) acc[j] = 0.f;
    int k = 0;
    for (; k + 7 < n; k += 8) {
        uint4 tv[8];
#pragma unroll
        for (int q = 0; q < 8; ++q) {
            int s = cr[k + q];
            tv[q] = xb4[(size_t)s * 16 + gl];
        }
#pragma unroll
        for (int q = 0; q < 8; ++q) {
            acc[0] += bflo(tv[q].x); acc[1] += bfhi(tv[q].x);
            acc[2] += bflo(tv[q].y); acc[3] += bfhi(tv[q].y);
            acc[4] += bflo(tv[q].z); acc[5] += bfhi(tv[q].z);
            acc[6] += bflo(tv[q].w); acc[7] += bfhi(tv[q].w);
        }
    }
    if (k + 3 < n) {
        uint4 tv[4];
#pragma unroll
        for (int q = 0; q < 4; ++q) {
            int s = cr[k + q];
            tv[q] = xb4[(size_t)s * 16 + gl];
        }
#pragma unroll
        for (int q = 0; q < 4; ++q) {
            acc[0] += bflo(tv[q].x); acc[1] += bfhi(tv[q].x);
            acc[2] += bflo(tv[q].y); acc[3] += bfhi(tv[q].y);
            acc[4] += bflo(tv[q].z); acc[5] += bfhi(tv[q].z);
            acc[6] += bflo(tv[q].w); acc[7] += bfhi(tv[q].w);
        }
        k += 4;
    }
    for (; k < n; ++k) {
        int s = cr[k];
        uint4 t0 = xb4[(size_t)s * 16 + gl];
        acc[0] += bflo(t0.x); acc[1] += bfhi(t0.x);
        acc[2] += bflo(t0.y); acc[3] += bfhi(t0.y);
        acc[4] += bflo(t0.z); acc[5] += bfhi(t0.z);
        acc[6] += bflo(t0.w); acc[7] += bfhi(t0.w);
    }
    float inv = 1.0f / fmaxf((float)n, 1.0f);
    uint4 o;
    o.x = bfpack(acc[0] * inv, acc[1] * inv);
    o.y = bfpack(acc[2] * inv, acc[3] * inv);
    o.z = bfpack(acc[4] * inv, acc[5] * inv);
    o.w = bfpack(acc[6] * inv, acc[7] * inv);

    *(uint4*)&Asu1[sg * 68 + gl * 4] = xs;
    *(uint4*)&Asu0[sg * 68 + gl * 4] = o;
    __syncthreads();  // (a) tiles visible

    // A fragments: row li (tile row), K chunk kc*32 + quad*8
    bf16x8 af0[4], af1[4];
#pragma unroll
    for (int kc = 0; kc < 4; ++kc) {
        af0[kc] = *(const bf16x8*)&Asu0[li * 68 + kc * 16 + quad * 4];
        af1[kc] = *(const bf16x8*)&Asu1[li * 68 + kc * 16 + quad * 4];
    }

    // GEMM1: wave w owns n-tiles {2w, 2w+1}; per nt: phase0 kc0-3, phase1 kc0-3
    f32x4 dacc[2];
#pragma unroll
    for (int j = 0; j < 2; ++j) dacc[j] = (f32x4){0.f, 0.f, 0.f, 0.f};
#pragma unroll
    for (int j = 0; j < 2; ++j) {
        int nt = wid * 2 + j;
#pragma unroll
        for (int kc = 0; kc < 4; ++kc) {
            bf16x8 bfr = *(const bf16x8*)(WfA + (size_t)(kc * 8 + nt) * 256 + lane * 4);
            dacc[j] = __builtin_amdgcn_mfma_f32_16x16x32_bf16(af0[kc], bfr, dacc[j], 0, 0, 0);
        }
#pragma unroll
        for (int kc = 0; kc < 4; ++kc) {
            bf16x8 bfr = *(const bf16x8*)(WfA + 8192 + (size_t)(kc * 8 + nt) * 256 + lane * 4);
            dacc[j] = __builtin_amdgcn_mfma_f32_16x16x32_bf16(af1[kc], bfr, dacc[j], 0, 0, 0);
        }
    }
    __syncthreads();  // (b) af0/af1 reads done before Hs overwrite

    // GEMM1 epilogue: bias + ReLU + BN -> h bf16 into Asu0
    unsigned short* Hs = (unsigned short*)Asu0;  // row stride 136 ushorts
#pragma unroll
    for (int j = 0; j < 2; ++j) {
        int nt = wid * 2 + j;
        int cgc = nt * 16 + li;
        float sc = gamma[cgc] * rsqrtf(rvar[cgc] + BN_EPS);
        float sh = fmaf(-rmean[cgc], sc, beta[cgc]);
        float bb = b1[cgc];
#pragma unroll
        for (int r = 0; r < 4; ++r) {
            int row = quad * 4 + r;  // local row 0..15
            float pre = dacc[j][r] + bb;
            Hs[row * 136 + cgc] = bfr1(fmaf(fmaxf(pre, 0.f), sc, sh));
        }
    }
    __syncthreads();  // (c) h visible

    // GEMM2: wave w owns n-tile w; wave 0 also owns n-tile 4
    bf16x8 af2[4];
#pragma unroll
    for (int kc = 0; kc < 4; ++kc)
        af2[kc] = *(const bf16x8*)&Asu0[li * 68 + kc * 16 + quad * 4];

    int nNT = (wid == 0) ? 2 : 1;
    f32x4 d2[2];
#pragma unroll
    for (int j = 0; j < 2; ++j) d2[j] = (f32x4){0.f, 0.f, 0.f, 0.f};
    for (int j = 0; j < nNT; ++j) {
        int nt = (j == 0) ? wid : 4;
#pragma unroll
        for (int kc = 0; kc < 4; ++kc) {
            bf16x8 bfr = *(const bf16x8*)(WfB + (size_t)(kc * 5 + nt) * 256 + lane * 4);
            d2[j] = __builtin_amdgcn_mfma_f32_16x16x32_bf16(af2[kc], bfr, d2[j], 0, 0, 0);
        }
    }
    for (int j = 0; j < nNT; ++j) {
        int nt = (j == 0) ? wid : 4;
        int cgc = nt * 16 + li;
#pragma unroll
        for (int r = 0; r < 4; ++r) {
            int row = tb + quad * 4 + r;  // always < 50000
            float vv = d2[j][r];
            if (cgc < 40) z2s[(size_t)row * 40 + cgc] = bfr1(vv);
            else p2[(size_t)row * 40 + (cgc - 40)] = vv;
        }
    }
}

// ---------------------------------------------------------------------------
// Gather layer 2 + final: 5 lanes x uint4 per 80B z2 row + LDS-staged CSR
// (r14 version, unchanged).
// ---------------------------------------------------------------------------
__global__ __launch_bounds__(256) void gather2_kernel(const unsigned short* __restrict__ csr_pad,
                                                      const int* __restrict__ deg_i,
                                                      const unsigned short* __restrict__ z2s,
                                                      const float* __restrict__ p2,
                                                      const float* __restrict__ b2,
                                                      float* __restrict__ out) {
    __shared__ __align__(16) unsigned short Cs[G2_SUB * 64];
    int t = threadIdx.x;
    int nb_base = blockIdx.x * G2_SUB;
    int nn = min(G2_SUB, N_NODES - nb_base);
    int limit_u2 = (nn * 64) >> 2;  // uint2 count
    const uint2* cg = (const uint2*)(csr_pad + (size_t)nb_base * 64);
    for (int i = t; i < limit_u2; i += 256) ((uint2*)Cs)[i] = cg[i];
    __syncthreads();

    int sub = t / 5;
    int li = t - sub * 5;      // 0..4, owns features [li*8, li*8+8)
    if (sub >= G2_SUB) return;
    int gid = nb_base + sub;
    if (gid >= N_NODES) return;
    int n = min(deg_i[gid], CSR_STRIDE);
    const unsigned short* cr = Cs + sub * 64;
    const uint4* z4 = (const uint4*)z2s;   // row = 5 uint4s
    float acc[8];
#pragma unroll
    for (int j = 0; j < 8; ++j) acc[j] = 0.f;
    int k = 0;
    for (; k + 7 < n; k += 8) {
        uint4 tv[8];
#pragma unroll
        for (int q = 0; q < 8; ++q) {
            int s = cr[k + q];
            tv[q] = z4[(size_t)s * 5 + li];
        }
#pragma unroll
        for (int q = 0; q < 8; ++q) {
            acc[0] += bflo(tv[q].x); acc[1] += bfhi(tv[q].x);
            acc[2] += bflo(tv[q].y); acc[3] += bfhi(tv[q].y);
            acc[4] += bflo(tv[q].z); acc[5] += bfhi(tv[q].z);
            acc[6] += bflo(tv[q].w); acc[7] += bfhi(tv[q].w);
        }
    }
    if (k + 3 < n) {
        uint4 tv[4];
#pragma unroll
        for (int q = 0; q < 4; ++q) {
            int s = cr[k + q];
            tv[q] = z4[(size_t)s * 5 + li];
        }
#pragma unroll
        for (int q = 0; q < 4; ++q) {
            acc[0] += bflo(tv[q].x); acc[1] += bfhi(tv[q].x);
            acc[2] += bflo(tv[q].y); acc[3] += bfhi(tv[q].y);
            acc[4] += bflo(tv[q].z); acc[5] += bfhi(tv[q].z);
            acc[6] += bflo(tv[q].w); acc[7] += bfhi(tv[q].w);
        }
        k += 4;
    }
    for (; k < n; ++k) {
        int s = cr[k];
        uint4 t0 = z4[(size_t)s * 5 + li];
        acc[0] += bflo(t0.x); acc[1] += bfhi(t0.x);
        acc[2] += bflo(t0.y); acc[3] += bfhi(t0.y);
        acc[4] += bflo(t0.z); acc[5] += bfhi(t0.z);
        acc[6] += bflo(t0.w); acc[7] += bfhi(t0.w);
    }
    float inv = 1.0f / fmaxf((float)n, 1.0f);
    const float4* p4 = (const float4*)p2;
    const float4* b4 = (const float4*)b2;
    float4 pa = p4[(size_t)gid * 10 + li * 2];
    float4 pb = p4[(size_t)gid * 10 + li * 2 + 1];
    float4 ba = b4[li * 2];
    float4 bb = b4[li * 2 + 1];
    float4 ra, rb;
    ra.x = fmaf(acc[0], inv, pa.x + ba.x);
    ra.y = fmaf(acc[1], inv, pa.y + ba.y);
    ra.z = fmaf(acc[2], inv, pa.z + ba.z);
    ra.w = fmaf(acc[3], inv, pa.w + ba.w);
    rb.x = fmaf(acc[4], inv, pb.x + bb.x);
    rb.y = fmaf(acc[5], inv, pb.y + bb.y);
    rb.z = fmaf(acc[6], inv, pb.z + bb.z);
    rb.w = fmaf(acc[7], inv, pb.w + bb.w);
    ((float4*)out)[(size_t)gid * 10 + li * 2] = ra;
    ((float4*)out)[(size_t)gid * 10 + li * 2 + 1] = rb;
}

// ---------------------------------------------------------------------------
// Launch: 4 dispatches. ws layout (int units):
//   deg_i[50048] (memset 0)
//   csr_pad ushort[50000*64] = 1,600,000 ints
//   WfA u32[16384], WfB u32[5120]
//   x_bf16 u32[3200000]  (row-major)
//   z2s ushort[50048*40] + p2 f32[50048*40]
// ---------------------------------------------------------------------------
extern "C" void kernel_launch(void* const* d_in, const int* in_sizes, int n_in,
                              void* d_out, int out_size, void* d_ws, size_t ws_size,
                              hipStream_t stream) {
    const float* x     = (const float*)d_in[0];
    const int*   ei    = (const int*)d_in[1];
    const float* W1l   = (const float*)d_in[2];
    const float* b1    = (const float*)d_in[3];
    const float* W1r   = (const float*)d_in[4];
    const float* gamma = (const float*)d_in[5];
    const float* beta  = (const float*)d_in[6];
    const float* rmean = (const float*)d_in[7];
    const float* rvar  = (const float*)d_in[8];
    const float* W2l   = (const float*)d_in[9];
    const float* b2    = (const float*)d_in[10];
    const float* W2r   = (const float*)d_in[11];
    float* out = (float*)d_out;

    int* deg_i              = (int*)d_ws;
    unsigned short* csr_pad = (unsigned short*)(deg_i + 50048);
    unsigned* WfA           = (unsigned*)(deg_i + 50048 + 1600000);
    unsigned* WfB           = WfA + 16384;
    unsigned* x_bf16        = WfB + 5120;
    unsigned short* z2s     = (unsigned short*)(x_bf16 + 3200000);
    float* p2               = (float*)(z2s + (size_t)50048 * 40);

    const int* src = ei;
    const int* dst = ei + N_EDGES;

    hipMemsetAsync(deg_i, 0, (size_t)50048 * sizeof(int), stream);

    degprep_kernel<<<CSR_B + WPACK_B + XPACK_B, 256, 0, stream>>>(
        src, dst, deg_i, csr_pad, W1l, W1r, W2l, W2r, x, WfA, WfB, x_bf16);

    gg_kernel<<<N_NODES / 16, 256, 0, stream>>>(
        csr_pad, deg_i, x_bf16, WfA, WfB, b1, gamma, beta, rmean, rvar, z2s, p2);

    gather2_kernel<<<(N_NODES + G2_SUB - 1) / G2_SUB, 256, 0, stream>>>(
        csr_pad, deg_i, z2s, p2, b2, out);
}

// Round 16
// 157.971 us; speedup vs baseline: 1.1578x; 1.1578x over previous
//
#include <hip/hip_runtime.h>

#define N_NODES 50000
#define N_EDGES 800000
#define N_FEAT 128
#define N_HID 128
#define N_CLS 40
#define BN_EPS 1e-5f

#define CSR_STRIDE 64   // padded CSR row stride; max degree ~40 (Poisson 16)
#define NBKT 196        // node buckets of 256 (dst >> 8); 196*256 = 50176
#define REC_CAP 6144    // records per bucket; mean 4081, 32-sigma headroom
#define PA_B 196        // phase-A blocks (1024 thr x 4 edges = 4096/block)
#define WPACK1K 21      // 21504 / 1024
#define XPACK1K 782     // ceil(800000 / 1024)
#define D1_B (PA_B + WPACK1K + XPACK1K)  // 999
#define G2_SUB 51       // gather2 nodes per block

typedef short bf16x8 __attribute__((ext_vector_type(8)));
typedef float f32x4 __attribute__((ext_vector_type(4)));

// RNE float->bf16 helpers
__device__ __forceinline__ unsigned bfpack(float a, float b) {
    unsigned ua = __float_as_uint(a), ub = __float_as_uint(b);
    ua = (ua + 0x7FFFu + ((ua >> 16) & 1u)) >> 16;
    ub = (ub + 0x7FFFu + ((ub >> 16) & 1u)) >> 16;
    return ua | (ub << 16);
}
__device__ __forceinline__ unsigned short bfr1(float a) {
    unsigned u = __float_as_uint(a);
    u = (u + 0x7FFFu + ((u >> 16) & 1u)) >> 16;
    return (unsigned short)u;
}
__device__ __forceinline__ float bflo(unsigned u) { return __uint_as_float(u << 16); }
__device__ __forceinline__ float bfhi(unsigned u) { return __uint_as_float(u & 0xFFFF0000u); }

// ---------------------------------------------------------------------------
// Dispatch 1: PHASE-A edge binning + weight pack + x pack (one kernel,
// 1024-thread blocks). Phase A replaces the scatter-atomic CSR build
// (service-limited at 44.6 us, WRITE 43 MB = 1 line/edge): edges are binned
// into 196 per-bucket record arrays. Ranks via LDS histogram; ONE global
// cursor atomic per (block,bucket) -> 38K atomics total (was 800K). Records
// are 4B (node_local | src<<16) written in ~21-record contiguous runs.
// ---------------------------------------------------------------------------
__global__ __launch_bounds__(1024) void d1_kernel(
    const int* __restrict__ src, const int* __restrict__ dst,
    int* __restrict__ gcur, unsigned* __restrict__ rec,
    const float* __restrict__ W1l, const float* __restrict__ W1r,
    const float* __restrict__ W2l, const float* __restrict__ W2r,
    const float* __restrict__ x, unsigned* __restrict__ WfA,
    unsigned* __restrict__ WfB, unsigned* __restrict__ x_bf16) {
    int b = blockIdx.x;
    int t = threadIdx.x;
    if (b < PA_B) {
        __shared__ int hist[NBKT];
        __shared__ int base[NBKT];
        if (t < NBKT) hist[t] = 0;
        __syncthreads();
        int e = b * 4096 + t * 4;
        bool val = e < N_EDGES;   // e % 4 == 0, so val => e+3 < N_EDGES
        int4 d4 = {0, 0, 0, 0}, s4 = {0, 0, 0, 0};
        int bk[4], rk[4];
        if (val) {
            d4 = ((const int4*)dst)[e >> 2];
            s4 = ((const int4*)src)[e >> 2];
            bk[0] = d4.x >> 8; rk[0] = atomicAdd(&hist[bk[0]], 1);
            bk[1] = d4.y >> 8; rk[1] = atomicAdd(&hist[bk[1]], 1);
            bk[2] = d4.z >> 8; rk[2] = atomicAdd(&hist[bk[2]], 1);
            bk[3] = d4.w >> 8; rk[3] = atomicAdd(&hist[bk[3]], 1);
        }
        __syncthreads();
        if (t < NBKT) base[t] = atomicAdd(&gcur[t], hist[t]);
        __syncthreads();
        if (val) {
            int dl[4] = {d4.x & 255, d4.y & 255, d4.z & 255, d4.w & 255};
            int sv[4] = {s4.x, s4.y, s4.z, s4.w};
#pragma unroll
            for (int q = 0; q < 4; ++q) {
                int pos = base[bk[q]] + rk[q];
                if (pos < REC_CAP)
                    rec[(size_t)bk[q] * REC_CAP + pos] =
                        (unsigned)dl[q] | ((unsigned)sv[q] << 16);
            }
        }
        return;
    }
    if (b < PA_B + WPACK1K) {
        int i = (b - PA_B) * 1024 + t;
        if (i < 16384) {
            int f = i >> 8, r = i & 255;
            int lane = r >> 2, u = r & 3;
            int phase = f >> 5, kc = (f >> 3) & 3, nt = f & 7;
            int k0 = phase * 128 + kc * 32 + (lane >> 4) * 8 + u * 2;
            int n = nt * 16 + (lane & 15);
            float w0, w1;
            if (k0 < 128) {
                w0 = W1l[n * 128 + k0];
                w1 = W1l[n * 128 + k0 + 1];
            } else {
                w0 = W1r[n * 128 + k0 - 128];
                w1 = W1r[n * 128 + k0 - 127];
            }
            WfA[i] = bfpack(w0, w1);
        } else if (i < 21504) {
            int j = i - 16384;
            int f = j >> 8, r = j & 255;
            int lane = r >> 2, u = r & 3;
            int kc = f / 5, nt = f % 5;
            int k0 = kc * 32 + (lane >> 4) * 8 + u * 2;
            int n = nt * 16 + (lane & 15);
            float w0, w1;
            if (n < 40) {
                w0 = W2l[n * 128 + k0];
                w1 = W2l[n * 128 + k0 + 1];
            } else {
                w0 = W2r[(n - 40) * 128 + k0];
                w1 = W2r[(n - 40) * 128 + k0 + 1];
            }
            WfB[j] = bfpack(w0, w1);
        }
    } else {
        int j = (b - PA_B - WPACK1K) * 1024 + t;
        if (j < 800000) {
            const float4* xf = (const float4*)x;
            float4 a = xf[(size_t)j * 2];
            float4 bq = xf[(size_t)j * 2 + 1];
            uint4 o;
            o.x = bfpack(a.x, a.y);
            o.y = bfpack(a.z, a.w);
            o.z = bfpack(bq.x, bq.y);
            o.w = bfpack(bq.z, bq.w);
            ((uint4*)x_bf16)[j] = o;
        }
    }
}

// ---------------------------------------------------------------------------
// PHASE-B: one block per bucket. Builds the bucket's 256-node padded CSR
// entirely in LDS (rank via LDS atomicAdd, csr tile 32 KB), then dumps
// csr+deg to global fully coalesced — zero scattered global stores.
// ---------------------------------------------------------------------------
__global__ __launch_bounds__(256) void phaseB_kernel(
    const int* __restrict__ gcur, const unsigned* __restrict__ rec,
    int* __restrict__ deg_i, unsigned short* __restrict__ csr_pad) {
    __shared__ __align__(16) unsigned short csr_l[256 * CSR_STRIDE];  // 32 KB
    __shared__ int deg_l[256];
    int t = threadIdx.x;
    int bid = blockIdx.x;
    deg_l[t] = 0;
    __syncthreads();
    int nrec = min(gcur[bid], REC_CAP);
    const unsigned* rb = rec + (size_t)bid * REC_CAP;
    for (int i = t; i < nrec; i += 256) {
        unsigned u = rb[i];
        int nl = (int)(u & 255u);
        unsigned short sv = (unsigned short)(u >> 16);
        int r = atomicAdd(&deg_l[nl], 1);
        if (r < CSR_STRIDE) csr_l[nl * CSR_STRIDE + r] = sv;
    }
    __syncthreads();
    int nb = bid * 256;
    int nn = min(256, N_NODES - nb);   // last bucket: 80
    if (t < nn) deg_i[nb + t] = deg_l[t];
    int n_u4 = nn * (CSR_STRIDE / 8);  // uint4 count (8 ushorts each)
    uint4* gout = (uint4*)(csr_pad + (size_t)nb * CSR_STRIDE);
    const uint4* lin = (const uint4*)csr_l;
    for (int i = t; i < n_u4; i += 256) gout[i] = lin[i];
}

// ---------------------------------------------------------------------------
// Fused GATHER1 + GEMM1 + GEMM2 at 16-ROW TILES (3125 blocks) + LDS-staged
// CSR (r14/r15 version, unchanged).
// ---------------------------------------------------------------------------
__global__ __launch_bounds__(256) void gg_kernel(
    const unsigned short* __restrict__ csr_pad, const int* __restrict__ deg_i,
    const unsigned* __restrict__ x_bf16,
    const unsigned* __restrict__ WfA, const unsigned* __restrict__ WfB,
    const float* __restrict__ b1,
    const float* __restrict__ gamma, const float* __restrict__ beta,
    const float* __restrict__ rmean, const float* __restrict__ rvar,
    unsigned short* __restrict__ z2s, float* __restrict__ p2) {
    __shared__ unsigned Asu0[16 * 68];  // gather result, then h (bf16)
    __shared__ unsigned Asu1[16 * 68];  // x tile (bf16)
    __shared__ __align__(16) unsigned short Cs[16 * 64];  // staged CSR rows
    const int t = threadIdx.x;
    const int wid = __builtin_amdgcn_readfirstlane(t >> 6);
    const int lane = t & 63;
    const int li = lane & 15;
    const int quad = lane >> 4;
    const int sg = t >> 4;   // node within tile / stage row
    const int gl = t & 15;   // feature segment
    const int tb = blockIdx.x * 16;   // 3125*16 = 50000, all rows valid
    const uint4* xb4 = (const uint4*)x_bf16;

    // issue x-tile stage load early; latency hides under the gather
    uint4 xs = xb4[(size_t)(tb + sg) * 16 + gl];
    // stage the block's 16 CSR rows: 1024 ushorts = 256 uint2, coalesced
    ((uint2*)Cs)[t] = ((const uint2*)(csr_pad + (size_t)tb * 64))[t];
    __syncthreads();  // Cs visible

    // ---- gather: subgroup sg owns node tb+sg (ILP-8, identical order) ----
    int gid = tb + sg;
    int n = min(deg_i[gid], CSR_STRIDE);
    const unsigned short* cr = Cs + sg * 64;
    float acc[8];
#pragma unroll
    for (int j = 0; j < 8; ++j) acc[j] = 0.f;
    int k = 0;
    for (; k + 7 < n; k += 8) {
        uint4 tv[8];
#pragma unroll
        for (int q = 0; q < 8; ++q) {
            int s = cr[k + q];
            tv[q] = xb4[(size_t)s * 16 + gl];
        }
#pragma unroll
        for (int q = 0; q < 8; ++q) {
            acc[0] += bflo(tv[q].x); acc[1] += bfhi(tv[q].x);
            acc[2] += bflo(tv[q].y); acc[3] += bfhi(tv[q].y);
            acc[4] += bflo(tv[q].z); acc[5] += bfhi(tv[q].z);
            acc[6] += bflo(tv[q].w); acc[7] += bfhi(tv[q].w);
        }
    }
    if (k + 3 < n) {
        uint4 tv[4];
#pragma unroll
        for (int q = 0; q < 4; ++q) {
            int s = cr[k + q];
            tv[q] = xb4[(size_t)s * 16 + gl];
        }
#pragma unroll
        for (int q = 0; q < 4; ++q) {
            acc[0] += bflo(tv[q].x); acc[1] += bfhi(tv[q].x);
            acc[2] += bflo(tv[q].y); acc[3] += bfhi(tv[q].y);
            acc[4] += bflo(tv[q].z); acc[5] += bfhi(tv[q].z);
            acc[6] += bflo(tv[q].w); acc[7] += bfhi(tv[q].w);
        }
        k += 4;
    }
    for (; k < n; ++k) {
        int s = cr[k];
        uint4 t0 = xb4[(size_t)s * 16 + gl];
        acc[0] += bflo(t0.x); acc[1] += bfhi(t0.x);
        acc[2] += bflo(t0.y); acc[3] += bfhi(t0.y);
        acc[4] += bflo(t0.z); acc[5] += bfhi(t0.z);
        acc[6] += bflo(t0.w); acc[7] += bfhi(t0.w);
    }
    float inv = 1.0f / fmaxf((float)n, 1.0f);
    uint4 o;
    o.x = bfpack(acc[0] * inv, acc[1] * inv);
    o.y = bfpack(acc[2] * inv, acc[3] * inv);
    o.z = bfpack(acc[4] * inv, acc[5] * inv);
    o.w = bfpack(acc[6] * inv, acc[7] * inv);

    *(uint4*)&Asu1[sg * 68 + gl * 4] = xs;
    *(uint4*)&Asu0[sg * 68 + gl * 4] = o;
    __syncthreads();  // (a) tiles visible

    // A fragments: row li (tile row), K chunk kc*32 + quad*8
    bf16x8 af0[4], af1[4];
#pragma unroll
    for (int kc = 0; kc < 4; ++kc) {
        af0[kc] = *(const bf16x8*)&Asu0[li * 68 + kc * 16 + quad * 4];
        af1[kc] = *(const bf16x8*)&Asu1[li * 68 + kc * 16 + quad * 4];
    }

    // GEMM1: wave w owns n-tiles {2w, 2w+1}; per nt: phase0 kc0-3, phase1 kc0-3
    f32x4 dacc[2];
#pragma unroll
    for (int j = 0; j < 2; ++j) dacc[j] = (f32x4){0.f, 0.f, 0.f, 0.f};
#pragma unroll
    for (int j = 0; j < 2; ++j) {
        int nt = wid * 2 + j;
#pragma unroll
        for (int kc = 0; kc < 4; ++kc) {
            bf16x8 bfr = *(const bf16x8*)(WfA + (size_t)(kc * 8 + nt) * 256 + lane * 4);
            dacc[j] = __builtin_amdgcn_mfma_f32_16x16x32_bf16(af0[kc], bfr, dacc[j], 0, 0, 0);
        }
#pragma unroll
        for (int kc = 0; kc < 4; ++kc) {
            bf16x8 bfr = *(const bf16x8*)(WfA + 8192 + (size_t)(kc * 8 + nt) * 256 + lane * 4);
            dacc[j] = __builtin_amdgcn_mfma_f32_16x16x32_bf16(af1[kc], bfr, dacc[j], 0, 0, 0);
        }
    }
    __syncthreads();  // (b) af0/af1 reads done before Hs overwrite

    // GEMM1 epilogue: bias + ReLU + BN -> h bf16 into Asu0
    unsigned short* Hs = (unsigned short*)Asu0;  // row stride 136 ushorts
#pragma unroll
    for (int j = 0; j < 2; ++j) {
        int nt = wid * 2 + j;
        int cgc = nt * 16 + li;
        float sc = gamma[cgc] * rsqrtf(rvar[cgc] + BN_EPS);
        float sh = fmaf(-rmean[cgc], sc, beta[cgc]);
        float bb = b1[cgc];
#pragma unroll
        for (int r = 0; r < 4; ++r) {
            int row = quad * 4 + r;  // local row 0..15
            float pre = dacc[j][r] + bb;
            Hs[row * 136 + cgc] = bfr1(fmaf(fmaxf(pre, 0.f), sc, sh));
        }
    }
    __syncthreads();  // (c) h visible

    // GEMM2: wave w owns n-tile w; wave 0 also owns n-tile 4
    bf16x8 af2[4];
#pragma unroll
    for (int kc = 0; kc < 4; ++kc)
        af2[kc] = *(const bf16x8*)&Asu0[li * 68 + kc * 16 + quad * 4];

    int nNT = (wid == 0) ? 2 : 1;
    f32x4 d2[2];
#pragma unroll
    for (int j = 0; j < 2; ++j) d2[j] = (f32x4){0.f, 0.f, 0.f, 0.f};
    for (int j = 0; j < nNT; ++j) {
        int nt = (j == 0) ? wid : 4;
#pragma unroll
        for (int kc = 0; kc < 4; ++kc) {
            bf16x8 bfr = *(const bf16x8*)(WfB + (size_t)(kc * 5 + nt) * 256 + lane * 4);
            d2[j] = __builtin_amdgcn_mfma_f32_16x16x32_bf16(af2[kc], bfr, d2[j], 0, 0, 0);
        }
    }
    for (int j = 0; j < nNT; ++j) {
        int nt = (j == 0) ? wid : 4;
        int cgc = nt * 16 + li;
#pragma unroll
        for (int r = 0; r < 4; ++r) {
            int row = tb + quad * 4 + r;  // always < 50000
            float vv = d2[j][r];
            if (cgc < 40) z2s[(size_t)row * 40 + cgc] = bfr1(vv);
            else p2[(size_t)row * 40 + (cgc - 40)] = vv;
        }
    }
}

// ---------------------------------------------------------------------------
// Gather layer 2 + final: 5 lanes x uint4 per 80B z2 row + LDS-staged CSR
// (r14/r15 version, unchanged).
// ---------------------------------------------------------------------------
__global__ __launch_bounds__(256) void gather2_kernel(const unsigned short* __restrict__ csr_pad,
                                                      const int* __restrict__ deg_i,
                                                      const unsigned short* __restrict__ z2s,
                                                      const float* __restrict__ p2,
                                                      const float* __restrict__ b2,
                                                      float* __restrict__ out) {
    __shared__ __align__(16) unsigned short Cs[G2_SUB * 64];
    int t = threadIdx.x;
    int nb_base = blockIdx.x * G2_SUB;
    int nn = min(G2_SUB, N_NODES - nb_base);
    int limit_u2 = (nn * 64) >> 2;  // uint2 count
    const uint2* cg = (const uint2*)(csr_pad + (size_t)nb_base * 64);
    for (int i = t; i < limit_u2; i += 256) ((uint2*)Cs)[i] = cg[i];
    __syncthreads();

    int sub = t / 5;
    int li = t - sub * 5;      // 0..4, owns features [li*8, li*8+8)
    if (sub >= G2_SUB) return;
    int gid = nb_base + sub;
    if (gid >= N_NODES) return;
    int n = min(deg_i[gid], CSR_STRIDE);
    const unsigned short* cr = Cs + sub * 64;
    const uint4* z4 = (const uint4*)z2s;   // row = 5 uint4s
    float acc[8];
#pragma unroll
    for (int j = 0; j < 8; ++j) acc[j] = 0.f;
    int k = 0;
    for (; k + 7 < n; k += 8) {
        uint4 tv[8];
#pragma unroll
        for (int q = 0; q < 8; ++q) {
            int s = cr[k + q];
            tv[q] = z4[(size_t)s * 5 + li];
        }
#pragma unroll
        for (int q = 0; q < 8; ++q) {
            acc[0] += bflo(tv[q].x); acc[1] += bfhi(tv[q].x);
            acc[2] += bflo(tv[q].y); acc[3] += bfhi(tv[q].y);
            acc[4] += bflo(tv[q].z); acc[5] += bfhi(tv[q].z);
            acc[6] += bflo(tv[q].w); acc[7] += bfhi(tv[q].w);
        }
    }
    if (k + 3 < n) {
        uint4 tv[4];
#pragma unroll
        for (int q = 0; q < 4; ++q) {
            int s = cr[k + q];
            tv[q] = z4[(size_t)s * 5 + li];
        }
#pragma unroll
        for (int q = 0; q < 4; ++q) {
            acc[0] += bflo(tv[q].x); acc[1] += bfhi(tv[q].x);
            acc[2] += bflo(tv[q].y); acc[3] += bfhi(tv[q].y);
            acc[4] += bflo(tv[q].z); acc[5] += bfhi(tv[q].z);
            acc[6] += bflo(tv[q].w); acc[7] += bfhi(tv[q].w);
        }
        k += 4;
    }
    for (; k < n; ++k) {
        int s = cr[k];
        uint4 t0 = z4[(size_t)s * 5 + li];
        acc[0] += bflo(t0.x); acc[1] += bfhi(t0.x);
        acc[2] += bflo(t0.y); acc[3] += bfhi(t0.y);
        acc[4] += bflo(t0.z); acc[5] += bfhi(t0.z);
        acc[6] += bflo(t0.w); acc[7] += bfhi(t0.w);
    }
    float inv = 1.0f / fmaxf((float)n, 1.0f);
    const float4* p4 = (const float4*)p2;
    const float4* b4 = (const float4*)b2;
    float4 pa = p4[(size_t)gid * 10 + li * 2];
    float4 pb = p4[(size_t)gid * 10 + li * 2 + 1];
    float4 ba = b4[li * 2];
    float4 bb = b4[li * 2 + 1];
    float4 ra, rb;
    ra.x = fmaf(acc[0], inv, pa.x + ba.x);
    ra.y = fmaf(acc[1], inv, pa.y + ba.y);
    ra.z = fmaf(acc[2], inv, pa.z + ba.z);
    ra.w = fmaf(acc[3], inv, pa.w + ba.w);
    rb.x = fmaf(acc[4], inv, pb.x + bb.x);
    rb.y = fmaf(acc[5], inv, pb.y + bb.y);
    rb.z = fmaf(acc[6], inv, pb.z + bb.z);
    rb.w = fmaf(acc[7], inv, pb.w + bb.w);
    ((float4*)out)[(size_t)gid * 10 + li * 2] = ra;
    ((float4*)out)[(size_t)gid * 10 + li * 2 + 1] = rb;
}

// ---------------------------------------------------------------------------
// Launch: 5 dispatches. ws layout (int units):
//   gcur[256] (memset 0 — only 1 KB now; deg memset eliminated)
//   rec u32[196*6144 = 1,204,224]
//   deg_i[50048]   (fully written by phaseB)
//   csr_pad ushort[50000*64] = 1,600,000 ints
//   WfA u32[16384], WfB u32[5120]
//   x_bf16 u32[3200000]  (row-major)
//   z2s ushort[50048*40] + p2 f32[50048*40]
// ---------------------------------------------------------------------------
extern "C" void kernel_launch(void* const* d_in, const int* in_sizes, int n_in,
                              void* d_out, int out_size, void* d_ws, size_t ws_size,
                              hipStream_t stream) {
    const float* x     = (const float*)d_in[0];
    const int*   ei    = (const int*)d_in[1];
    const float* W1l   = (const float*)d_in[2];
    const float* b1    = (const float*)d_in[3];
    const float* W1r   = (const float*)d_in[4];
    const float* gamma = (const float*)d_in[5];
    const float* beta  = (const float*)d_in[6];
    const float* rmean = (const float*)d_in[7];
    const float* rvar  = (const float*)d_in[8];
    const float* W2l   = (const float*)d_in[9];
    const float* b2    = (const float*)d_in[10];
    const float* W2r   = (const float*)d_in[11];
    float* out = (float*)d_out;

    int* gcur               = (int*)d_ws;
    unsigned* rec           = (unsigned*)(gcur + 256);
    int* deg_i              = (int*)(rec + (size_t)NBKT * REC_CAP);
    unsigned short* csr_pad = (unsigned short*)(deg_i + 50048);
    unsigned* WfA           = (unsigned*)(deg_i + 50048 + 1600000);
    unsigned* WfB           = WfA + 16384;
    unsigned* x_bf16        = WfB + 5120;
    unsigned short* z2s     = (unsigned short*)(x_bf16 + 3200000);
    float* p2               = (float*)(z2s + (size_t)50048 * 40);

    const int* src = ei;
    const int* dst = ei + N_EDGES;

    hipMemsetAsync(gcur, 0, 256 * sizeof(int), stream);

    d1_kernel<<<D1_B, 1024, 0, stream>>>(
        src, dst, gcur, rec, W1l, W1r, W2l, W2r, x, WfA, WfB, x_bf16);

    phaseB_kernel<<<NBKT, 256, 0, stream>>>(gcur, rec, deg_i, csr_pad);

    gg_kernel<<<N_NODES / 16, 256, 0, stream>>>(
        csr_pad, deg_i, x_bf16, WfA, WfB, b1, gamma, beta, rmean, rvar, z2s, p2);

    gather2_kernel<<<(N_NODES + G2_SUB - 1) / G2_SUB, 256, 0, stream>>>(
        csr_pad, deg_i, z2s, p2, b2, out);
}